// Round 9
// baseline (387.112 us; speedup 1.0000x reference)
//
#include <hip/hip_runtime.h>
#include <math.h>

// RouterLite v7 = v6.1 (passed, 353us) + occupancy fixes for the two
// grid-capped MFMA kernels (both were 2 waves/SIMD by grid arithmetic):
//   kA_attn: r-splits 8 -> 16  (grid 64x16, 4 waves/SIMD)
//   k2_mfma: tile 64x128 -> 32x128 (grid 256x2x2, 16 waves/CU)
//
// ws map (float offsets), total ~62.4 MB:
//   Xbf  @0         [8192][2048] bf16 (8388608 fl) — dead after k2_mfma,
//                   ALIASED by OP @0 [16][4096][128] fp32 (exactly 8388608 fl)
//   HP   @8388608   [2][8192][256] fp32 partials (k2->k3, dead after)
//   Wbf  @12582912  [512][2048] bf16 (W1q rows 0..255, W1r 256..511)
//   Z    @13107200  [8192][128] fp32
//   Zbf  @14155776  [8192][128] bf16
//   ZbfT @14680064  [128][4096] bf16 (Z_r transposed)
//   RB   @14942208  [4096][128]
//   COS  @15466496  [4096]
//   ILW  @15470592  [4096][2]
//   LW   @15478784  [16][4096][2]
// d_out: fp32, [0..4095]=raw_logit, [4096..8191]=delta_theta.

#define HD   2048
#define D2   256
#define DD   128
#define NQ   4096
#define NT   8192

typedef __attribute__((ext_vector_type(8))) short s16x8;
typedef __attribute__((ext_vector_type(4))) float f32x4;

static __device__ __forceinline__ float gelu_exact(float x){
    return 0.5f * x * (1.0f + erff(x * 0.7071067811865475f));
}
static __device__ __forceinline__ unsigned short f2bf(float f){
    unsigned int u = __float_as_uint(f);
    return (unsigned short)((u + 0x7FFFu + ((u >> 16) & 1u)) >> 16);
}
static __device__ __forceinline__ unsigned int pack2bf(float a, float b){
    return (unsigned int)f2bf(a) | ((unsigned int)f2bf(b) << 16);
}

// ---------------- KLN: LN(x) -> bf16 Xbf (blocks 0..8191); W1 -> bf16 Wbf (8192..8703)
__global__ __launch_bounds__(256)
void kLN_cast(const float* __restrict__ q, const float* __restrict__ R,
              const float* __restrict__ gq, const float* __restrict__ bq,
              const float* __restrict__ gr, const float* __restrict__ br,
              const float* __restrict__ W1q, const float* __restrict__ W1r,
              unsigned short* __restrict__ Xbf, unsigned short* __restrict__ Wbf){
    const int r = blockIdx.x;
    const int tid = threadIdx.x;
    if (r >= NT){
        const int rw = r - NT;
        const float* src = (rw >= 256) ? (W1r + (size_t)(rw - 256) * HD)
                                       : (W1q + (size_t)rw * HD);
        float4 a = *(const float4*)&src[tid * 8];
        float4 c = *(const float4*)&src[tid * 8 + 4];
        uint4 p = {pack2bf(a.x, a.y), pack2bf(a.z, a.w),
                   pack2bf(c.x, c.y), pack2bf(c.z, c.w)};
        *(uint4*)&Wbf[(size_t)rw * HD + tid * 8] = p;
        return;
    }
    const float* src = (r < NQ) ? (q + (size_t)r * HD) : (R + (size_t)(r - NQ) * HD);
    const float* g  = (r < NQ) ? gq : gr;
    const float* bb = (r < NQ) ? bq : br;
    float4 x0 = *(const float4*)&src[tid * 8];
    float4 x1 = *(const float4*)&src[tid * 8 + 4];
    float v[8] = {x0.x, x0.y, x0.z, x0.w, x1.x, x1.y, x1.z, x1.w};
    float s = 0.f, sq = 0.f;
#pragma unroll
    for (int i = 0; i < 8; ++i){ s += v[i]; sq += v[i] * v[i]; }
    __shared__ float red[256];
    __shared__ float mS, rS;
    red[tid] = s; __syncthreads();
    for (int off = 128; off > 0; off >>= 1){
        if (tid < off) red[tid] += red[tid + off];
        __syncthreads();
    }
    float sum = red[0]; __syncthreads();
    red[tid] = sq; __syncthreads();
    for (int off = 128; off > 0; off >>= 1){
        if (tid < off) red[tid] += red[tid + off];
        __syncthreads();
    }
    if (tid == 0){
        float mean = sum * (1.0f / HD);
        float var  = red[0] * (1.0f / HD) - mean * mean;
        mS = mean;
        rS = rsqrtf(fmaxf(var, 0.0f) + 1e-5f);
    }
    __syncthreads();
    float mean = mS, rstd = rS;
    float4 g0 = *(const float4*)&g[tid * 8];
    float4 g1 = *(const float4*)&g[tid * 8 + 4];
    float4 b0 = *(const float4*)&bb[tid * 8];
    float4 b1 = *(const float4*)&bb[tid * 8 + 4];
    float gg[8] = {g0.x, g0.y, g0.z, g0.w, g1.x, g1.y, g1.z, g1.w};
    float bv[8] = {b0.x, b0.y, b0.z, b0.w, b1.x, b1.y, b1.z, b1.w};
    float h[8];
#pragma unroll
    for (int i = 0; i < 8; ++i) h[i] = (v[i] - mean) * rstd * gg[i] + bv[i];
    uint4 p = {pack2bf(h[0], h[1]), pack2bf(h[2], h[3]),
               pack2bf(h[4], h[5]), pack2bf(h[6], h[7])};
    *(uint4*)&Xbf[(size_t)r * HD + tid * 8] = p;
}

// ---------------- K2: HP[ks] = Xbf @ Wbf^T (K-half ks), bf16 MFMA.
// grid (256 m-blocks of 32, 2 n-blocks of 128, 2 K-splits), 256 thr = 4 waves.
// Wave: 16m x 64n = 4 tiles of 16x16 (independent MFMA chains).
__global__ __launch_bounds__(256)
void k2_mfma(const unsigned short* __restrict__ Xbf,
             const unsigned short* __restrict__ Wbf,
             float* __restrict__ HP){
    const int tid  = threadIdx.x;
    const int wave = tid >> 6, lane = tid & 63;
    const int quad = lane >> 4, col = lane & 15;
    const int mblk = blockIdx.x;           // 0..255
    const int nblk = blockIdx.y;           // 0..1
    const int ks   = blockIdx.z;           // 0..1
    const int inp  = mblk >> 7;
    const int mbase = mblk * 32 + (wave & 1) * 16;
    const int nbase = nblk * 128 + (wave >> 1) * 64;

    const unsigned short* A0 = Xbf + (size_t)(mbase + col) * HD + ks * 1024 + quad * 8;
    const unsigned short* B0 = Wbf + (size_t)(inp * 256 + nbase + col) * HD + ks * 1024 + quad * 8;
    const unsigned short* B1 = B0 + (size_t)16 * HD;
    const unsigned short* B2 = B0 + (size_t)32 * HD;
    const unsigned short* B3 = B0 + (size_t)48 * HD;

    f32x4 acc[4];
#pragma unroll
    for (int ni = 0; ni < 4; ++ni) acc[ni] = (f32x4){0.f, 0.f, 0.f, 0.f};

    for (int s = 0; s < 32; ++s){
        const int ko = s * 32;
        s16x8 a0 = *(const s16x8*)(A0 + ko);
        s16x8 b0 = *(const s16x8*)(B0 + ko);
        s16x8 b1 = *(const s16x8*)(B1 + ko);
        s16x8 b2 = *(const s16x8*)(B2 + ko);
        s16x8 b3 = *(const s16x8*)(B3 + ko);
        acc[0] = __builtin_amdgcn_mfma_f32_16x16x32_bf16(a0, b0, acc[0], 0, 0, 0);
        acc[1] = __builtin_amdgcn_mfma_f32_16x16x32_bf16(a0, b1, acc[1], 0, 0, 0);
        acc[2] = __builtin_amdgcn_mfma_f32_16x16x32_bf16(a0, b2, acc[2], 0, 0, 0);
        acc[3] = __builtin_amdgcn_mfma_f32_16x16x32_bf16(a0, b3, acc[3], 0, 0, 0);
    }
    float* dst = HP + (size_t)ks * NT * D2;
#pragma unroll
    for (int ni = 0; ni < 4; ++ni){
#pragma unroll
        for (int reg = 0; reg < 4; ++reg){
            int m = mbase + quad * 4 + reg;
            int n = nbase + ni * 16 + col;
            dst[(size_t)m * D2 + n] = acc[ni][reg];
        }
    }
}

// ---------------- K3: combine HP + bias + GELU, GEMM2, l2norm -> Z (fp32), Zbf (bf16)
__global__ __launch_bounds__(256)
void k3_gemm2(const float* __restrict__ HP,
              const float* __restrict__ b1q, const float* __restrict__ b1r,
              const float* __restrict__ W2q, const float* __restrict__ b2q,
              const float* __restrict__ W2r, const float* __restrict__ b2r,
              float* __restrict__ Z, unsigned short* __restrict__ Zbf){
    const int gstart = blockIdx.x * 32;
    const int inp = (gstart >= NQ) ? 1 : 0;
    const float* b1 = inp ? b1r : b1q;
    const float* W2 = inp ? W2r : W2q;
    const float* b2 = inp ? b2r : b2q;

    __shared__ __align__(16) float Hs[32][68];
    __shared__ __align__(16) float Wk[64][132];
    __shared__ float red[32][17];
    __shared__ float normS[32];

    const int tid = threadIdx.x;
    const int ty = tid >> 4;
    const int tx = tid & 15;

    float acc[2][8];
#pragma unroll
    for (int jj = 0; jj < 8; ++jj){ acc[0][jj] = 0.f; acc[1][jj] = 0.f; }

    for (int kc = 0; kc < 4; ++kc){
#pragma unroll
        for (int i = 0; i < 8; ++i){
            int e = tid + i * 256;
            int rr = e >> 6, kk = e & 63;
            size_t idx = (size_t)(gstart + rr) * D2 + kc * 64 + kk;
            float hv = HP[idx] + HP[(size_t)NT * D2 + idx] + b1[kc * 64 + kk];
            Hs[rr][kk] = gelu_exact(hv);
        }
#pragma unroll
        for (int i = 0; i < 32; ++i){
            int e = tid + i * 256;
            int nn = e >> 6, kk = e & 63;
            Wk[kk][nn] = W2[(size_t)nn * D2 + kc * 64 + kk];
        }
        __syncthreads();
#pragma unroll
        for (int k4 = 0; k4 < 16; ++k4){
            float a0[4], a1[4];
            float4 t0 = *(const float4*)&Hs[ty * 2][k4 * 4];
            a0[0] = t0.x; a0[1] = t0.y; a0[2] = t0.z; a0[3] = t0.w;
            float4 t1 = *(const float4*)&Hs[ty * 2 + 1][k4 * 4];
            a1[0] = t1.x; a1[1] = t1.y; a1[2] = t1.z; a1[3] = t1.w;
#pragma unroll
            for (int kq = 0; kq < 4; ++kq){
                float4 w0 = *(const float4*)&Wk[k4 * 4 + kq][tx * 8];
                float4 w1 = *(const float4*)&Wk[k4 * 4 + kq][tx * 8 + 4];
                float wv[8] = {w0.x, w0.y, w0.z, w0.w, w1.x, w1.y, w1.z, w1.w};
#pragma unroll
                for (int jj = 0; jj < 8; ++jj){
                    acc[0][jj] += a0[kq] * wv[jj];
                    acc[1][jj] += a1[kq] * wv[jj];
                }
            }
        }
        __syncthreads();
    }
    float v0[8], v1[8];
    float sq0 = 0.f, sq1 = 0.f;
#pragma unroll
    for (int jj = 0; jj < 8; ++jj){
        int c = tx * 8 + jj;
        v0[jj] = acc[0][jj] + b2[c];
        v1[jj] = acc[1][jj] + b2[c];
        sq0 += v0[jj] * v0[jj];
        sq1 += v1[jj] * v1[jj];
    }
    red[ty * 2][tx]     = sq0;
    red[ty * 2 + 1][tx] = sq1;
    __syncthreads();
    if (tid < 32){
        float s = 0.f;
#pragma unroll
        for (int t = 0; t < 16; ++t) s += red[tid][t];
        normS[tid] = 1.0f / fmaxf(sqrtf(s), 1e-12f);
    }
    __syncthreads();
    float s0 = normS[ty * 2], s1 = normS[ty * 2 + 1];
    int row0 = gstart + ty * 2, row1 = row0 + 1;
    size_t o0 = (size_t)row0 * DD + tx * 8;
    size_t o1 = (size_t)row1 * DD + tx * 8;
    float z0[8], z1[8];
#pragma unroll
    for (int jj = 0; jj < 8; ++jj){ z0[jj] = v0[jj] * s0; z1[jj] = v1[jj] * s1; }
    float4 a = {z0[0], z0[1], z0[2], z0[3]}, b = {z0[4], z0[5], z0[6], z0[7]};
    float4 c = {z1[0], z1[1], z1[2], z1[3]}, d = {z1[4], z1[5], z1[6], z1[7]};
    *(float4*)&Z[o0]     = a;  *(float4*)&Z[o0 + 4] = b;
    *(float4*)&Z[o1]     = c;  *(float4*)&Z[o1 + 4] = d;
    uint4 p0 = {pack2bf(z0[0], z0[1]), pack2bf(z0[2], z0[3]),
                pack2bf(z0[4], z0[5]), pack2bf(z0[6], z0[7])};
    uint4 p1 = {pack2bf(z1[0], z1[1]), pack2bf(z1[2], z1[3]),
                pack2bf(z1[4], z1[5]), pack2bf(z1[6], z1[7])};
    *(uint4*)&Zbf[o0] = p0;
    *(uint4*)&Zbf[o1] = p1;
}

// ---------------- KT: ZbfT[d][r] = Zbf[NQ + r][d]  (r part only), tile 64x128.
__global__ __launch_bounds__(256)
void kT_transpose(const unsigned short* __restrict__ Zbf,
                  unsigned short* __restrict__ ZbfT){
    __shared__ unsigned short Ts[64][129];
    const int r0 = blockIdx.x * 64;
    const int tid = threadIdx.x;
#pragma unroll
    for (int i = 0; i < 32; ++i){
        int e = tid + i * 256;
        int rr = e >> 7, dd = e & 127;
        Ts[rr][dd] = Zbf[(size_t)(NQ + r0 + rr) * DD + dd];
    }
    __syncthreads();
#pragma unroll
    for (int i = 0; i < 32; ++i){
        int e = tid + i * 256;
        int dd = e >> 6, rr = e & 63;
        ZbfT[(size_t)dd * NQ + r0 + rr] = Ts[rr][dd];
    }
}

// ---------------- KA: flash attention pass (bf16 MFMA), 16 r-splits.
// grid (64 m-blocks, 16 r-splits), 256 thr = 4 waves, each wave = 16 q rows.
__global__ __launch_bounds__(256)
void kA_attn(const unsigned short* __restrict__ Zbf,
             const unsigned short* __restrict__ ZbfT,
             float* __restrict__ OP, float* __restrict__ LW){
    const int tid  = threadIdx.x;
    const int wave = tid >> 6, lane = tid & 63;
    const int quad = lane >> 4, col = lane & 15;
    const int m0   = blockIdx.x * 64 + wave * 16;
    const int split = blockIdx.y;          // 0..15
    const float scl = 0.08838834764831845f;   // 1/sqrt(128)

    __shared__ __align__(16) unsigned short Pt[4][16][72];  // per-wave [m][r]

    s16x8 aq[4];
#pragma unroll
    for (int kb = 0; kb < 4; ++kb)
        aq[kb] = *(const s16x8*)&Zbf[(size_t)(m0 + col) * DD + kb * 32 + quad * 8];

    f32x4 o[8];
#pragma unroll
    for (int dt = 0; dt < 8; ++dt) o[dt] = (f32x4){0.f, 0.f, 0.f, 0.f};
    float lp[4] = {0.f, 0.f, 0.f, 0.f}, wp[4] = {0.f, 0.f, 0.f, 0.f};

    for (int it = 0; it < 4; ++it){
        const int r0 = split * 256 + it * 64;
#pragma unroll
        for (int nt = 0; nt < 4; ++nt){
            f32x4 s = (f32x4){0.f, 0.f, 0.f, 0.f};
#pragma unroll
            for (int kb = 0; kb < 4; ++kb){
                s16x8 b = *(const s16x8*)&Zbf[(size_t)(NQ + r0 + nt * 16 + col) * DD + kb * 32 + quad * 8];
                s = __builtin_amdgcn_mfma_f32_16x16x32_bf16(aq[kb], b, s, 0, 0, 0);
            }
#pragma unroll
            for (int reg = 0; reg < 4; ++reg){
                float sv = s[reg] * scl;
                float e  = __expf(sv);
                lp[reg] += e;
                wp[reg] += e * sv;
                Pt[wave][quad * 4 + reg][nt * 16 + col] = f2bf(e);
            }
        }
        s16x8 ap[2];
#pragma unroll
        for (int kb2 = 0; kb2 < 2; ++kb2)
            ap[kb2] = *(const s16x8*)&Pt[wave][col][kb2 * 32 + quad * 8];
#pragma unroll
        for (int dt = 0; dt < 8; ++dt){
#pragma unroll
            for (int kb2 = 0; kb2 < 2; ++kb2){
                s16x8 b = *(const s16x8*)&ZbfT[(size_t)(dt * 16 + col) * NQ + r0 + kb2 * 32 + quad * 8];
                o[dt] = __builtin_amdgcn_mfma_f32_16x16x32_bf16(ap[kb2], b, o[dt], 0, 0, 0);
            }
        }
    }
#pragma unroll
    for (int reg = 0; reg < 4; ++reg){
        float l = lp[reg], w = wp[reg];
        l += __shfl_xor(l, 8);  w += __shfl_xor(w, 8);
        l += __shfl_xor(l, 4);  w += __shfl_xor(w, 4);
        l += __shfl_xor(l, 2);  w += __shfl_xor(w, 2);
        l += __shfl_xor(l, 1);  w += __shfl_xor(w, 1);
        if (col == 0){
            int row = m0 + quad * 4 + reg;
            LW[((size_t)split * NQ + row) * 2]     = l;
            LW[((size_t)split * NQ + row) * 2 + 1] = w;
        }
    }
#pragma unroll
    for (int dt = 0; dt < 8; ++dt){
#pragma unroll
        for (int reg = 0; reg < 4; ++reg){
            int row = m0 + quad * 4 + reg;
            OP[((size_t)split * NQ + row) * DD + dt * 16 + col] = o[dt][reg];
        }
    }
}

// ---------------- KC: combine 16 splits -> r_bar, cos, u_n.
__global__ __launch_bounds__(128)
void kC_combine(const float* __restrict__ OP, const float* __restrict__ LW,
                const float* __restrict__ Z,
                float* __restrict__ RB, float* __restrict__ COS,
                float* __restrict__ ILW){
    const int r = blockIdx.x;
    const int c = threadIdx.x;
    float v = 0.f;
#pragma unroll
    for (int s = 0; s < 16; ++s) v += OP[((size_t)s * NQ + r) * DD + c];
    __shared__ float red[128];
    red[c] = v * v; __syncthreads();
    for (int off = 64; off > 0; off >>= 1){
        if (c < off) red[c] += red[c + off];
        __syncthreads();
    }
    float scale = 1.0f / fmaxf(sqrtf(red[0]), 1e-12f);
    __syncthreads();
    float rb = v * scale;
    RB[(size_t)r * DD + c] = rb;
    float zq = Z[(size_t)r * DD + c];
    red[c] = zq * rb; __syncthreads();
    for (int off = 64; off > 0; off >>= 1){
        if (c < off) red[c] += red[c + off];
        __syncthreads();
    }
    if (c == 0){
        COS[r] = red[0];
        float l = 0.f, w = 0.f;
#pragma unroll
        for (int s = 0; s < 16; ++s){
            l += LW[((size_t)s * NQ + r) * 2];
            w += LW[((size_t)s * NQ + r) * 2 + 1];
        }
        float ent = logf(l) - w / l;
        ILW[2 * r]     = 1.0f / l;
        ILW[2 * r + 1] = ent * (1.0f / 8.317766166719343f);  // / ln(4096)
    }
}

// ---------------- K8: decoder MLP (LN -> 256->128 GELU -> 128->1) + scalar heads
__global__ __launch_bounds__(256)
void k8_decoder(const float* __restrict__ Z, const float* __restrict__ RB,
                const float* __restrict__ ILW, const float* __restrict__ COS,
                const float* __restrict__ gd, const float* __restrict__ bd,
                const float* __restrict__ W1d, const float* __restrict__ b1d,
                const float* __restrict__ W2d, const float* __restrict__ b2d,
                const float* __restrict__ beta, const float* __restrict__ W_len,
                const float* __restrict__ b_len,
                float* __restrict__ out){
    const int r0 = blockIdx.x * 16;
    const int tid = threadIdx.x;

    __shared__ __align__(16) float Xk[256][20];
    __shared__ __align__(16) float Wd[32][132];
    __shared__ float Hd[16][132];
    __shared__ float red1[16][17], red2[16][17];
    __shared__ float mS[16], rS[16];

#pragma unroll
    for (int i = 0; i < 16; ++i){
        int e = tid + i * 256;
        int rr = e >> 8, cc = e & 255;
        float v = (cc < DD) ? Z[(size_t)(r0 + rr) * DD + cc]
                            : RB[(size_t)(r0 + rr) * DD + (cc - DD)];
        Xk[cc][rr] = v;
    }
    __syncthreads();
    {
        const int row = tid >> 4, sub = tid & 15;
        float s = 0.f, sq = 0.f;
#pragma unroll
        for (int i = 0; i < 16; ++i){
            float v = Xk[sub + 16 * i][row];
            s += v; sq += v * v;
        }
        red1[row][sub] = s; red2[row][sub] = sq;
        __syncthreads();
        if (sub == 0){
            float ts = 0.f, tq = 0.f;
#pragma unroll
            for (int t = 0; t < 16; ++t){ ts += red1[row][t]; tq += red2[row][t]; }
            float mean = ts * (1.0f / D2);
            float var  = tq * (1.0f / D2) - mean * mean;
            var = fmaxf(var, 0.f);
            mS[row] = mean; rS[row] = rsqrtf(var + 1e-5f);
        }
        __syncthreads();
    }
#pragma unroll
    for (int i = 0; i < 16; ++i){
        int e = tid + i * 256;
        int rr = e >> 8, cc = e & 255;
        float v = Xk[cc][rr];
        Xk[cc][rr] = (v - mS[rr]) * rS[rr] * gd[cc] + bd[cc];
    }
    __syncthreads();

    const int j  = tid & 127;
    const int rh = tid >> 7;
    float hacc[8];
    {
        float bj = b1d[j];
#pragma unroll
        for (int i = 0; i < 8; ++i) hacc[i] = bj;
    }
    for (int kc = 0; kc < 8; ++kc){
#pragma unroll
        for (int i = 0; i < 16; ++i){
            int e = tid + i * 256;
            int nn = e >> 5, kk = e & 31;
            Wd[kk][nn] = W1d[(size_t)nn * D2 + kc * 32 + kk];
        }
        __syncthreads();
#pragma unroll
        for (int k = 0; k < 32; ++k){
            float w = Wd[k][j];
            int kk = kc * 32 + k;
            float4 x0 = *(const float4*)&Xk[kk][rh * 8];
            float4 x1 = *(const float4*)&Xk[kk][rh * 8 + 4];
            hacc[0] += x0.x * w; hacc[1] += x0.y * w;
            hacc[2] += x0.z * w; hacc[3] += x0.w * w;
            hacc[4] += x1.x * w; hacc[5] += x1.y * w;
            hacc[6] += x1.z * w; hacc[7] += x1.w * w;
        }
        __syncthreads();
    }
#pragma unroll
    for (int i = 0; i < 8; ++i) Hd[rh * 8 + i][j] = gelu_exact(hacc[i]);
    __syncthreads();
    {
        const int row = tid >> 4, sub = tid & 15;
        float part = 0.f;
#pragma unroll
        for (int i = 0; i < 8; ++i){
            int jj = sub + 16 * i;
            part += Hd[row][jj] * W2d[jj];
        }
        red1[row][sub] = part;
        __syncthreads();
        if (sub == 0){
            float lg = b2d[0];
#pragma unroll
            for (int t = 0; t < 16; ++t) lg += red1[row][t];
            int gr = r0 + row;
            float u  = ILW[2 * gr + 1];
            float cv = COS[gr];
            float dln = cv * W_len[0] + u * W_len[1] + b_len[0];
            float dt = beta[0] * u + beta[1] * tanhf(dln);
            dt = fminf(0.5f, fmaxf(-0.5f, dt));
            out[gr]      = lg;
            out[NQ + gr] = dt;
        }
    }
}

extern "C" void kernel_launch(void* const* d_in, const int* in_sizes, int n_in,
                              void* d_out, int out_size, void* d_ws, size_t ws_size,
                              hipStream_t stream){
    const float* q      = (const float*)d_in[0];
    const float* R      = (const float*)d_in[1];
    const float* ln_q_g = (const float*)d_in[2];
    const float* ln_q_b = (const float*)d_in[3];
    const float* W1q    = (const float*)d_in[4];
    const float* b1q    = (const float*)d_in[5];
    const float* W2q    = (const float*)d_in[6];
    const float* b2q    = (const float*)d_in[7];
    const float* ln_r_g = (const float*)d_in[8];
    const float* ln_r_b = (const float*)d_in[9];
    const float* W1r    = (const float*)d_in[10];
    const float* b1r    = (const float*)d_in[11];
    const float* W2r    = (const float*)d_in[12];
    const float* b2r    = (const float*)d_in[13];
    const float* ln_d_g = (const float*)d_in[14];
    const float* ln_d_b = (const float*)d_in[15];
    const float* W1d    = (const float*)d_in[16];
    const float* b1d    = (const float*)d_in[17];
    const float* W2d    = (const float*)d_in[18];
    const float* b2d    = (const float*)d_in[19];
    const float* beta   = (const float*)d_in[20];
    const float* W_len  = (const float*)d_in[21];
    const float* b_len  = (const float*)d_in[22];

    float* WS = (float*)d_ws;
    unsigned short* Xbf  = (unsigned short*)(WS);             // 8192*2048 bf16 = 8388608 fl
    float* OP    = WS;                                        // [16][4096][128] aliases dead Xbf
    float* HP    = WS + 8388608;                              // 2*8192*256
    unsigned short* Wbf  = (unsigned short*)(WS + 12582912);  // 512*2048 bf16
    float* Z     = WS + 13107200;                             // 8192*128
    unsigned short* Zbf  = (unsigned short*)(WS + 14155776);  // 8192*128 bf16
    unsigned short* ZbfT = (unsigned short*)(WS + 14680064);  // 128*4096 bf16
    float* RB    = WS + 14942208;                             // 4096*128
    float* COSV  = WS + 15466496;                             // 4096
    float* ILW   = WS + 15470592;                             // 4096*2
    float* LW    = WS + 15478784;                             // 16*4096*2
    float* out   = (float*)d_out;

    hipLaunchKernelGGL(kLN_cast, dim3(NT + 512), dim3(256), 0, stream,
                       q, R, ln_q_g, ln_q_b, ln_r_g, ln_r_b, W1q, W1r, Xbf, Wbf);
    hipLaunchKernelGGL(k2_mfma, dim3(256, 2, 2), dim3(256), 0, stream, Xbf, Wbf, HP);
    hipLaunchKernelGGL(k3_gemm2, dim3(256), dim3(256), 0, stream,
                       HP, b1q, b1r, W2q, b2q, W2r, b2r, Z, Zbf);
    hipLaunchKernelGGL(kT_transpose, dim3(64), dim3(256), 0, stream, Zbf, ZbfT);
    hipLaunchKernelGGL(kA_attn, dim3(64, 16), dim3(256), 0, stream, Zbf, ZbfT, OP, LW);
    hipLaunchKernelGGL(kC_combine, dim3(NQ), dim3(128), 0, stream, OP, LW, Z, RB, COSV, ILW);
    hipLaunchKernelGGL(k8_decoder, dim3(256), dim3(256), 0, stream,
                       Z, RB, ILW, COSV, ln_d_g, ln_d_b, W1d, b1d, W2d, b2d,
                       beta, W_len, b_len, out);
}

// Round 10
// 362.227 us; speedup vs baseline: 1.0687x; 1.0687x over previous
//
#include <hip/hip_runtime.h>
#include <math.h>

// RouterLite v8 = v7 (passed, 387us) with k2_mfma fixed: v7's 32m retile
// REGRESSED (77us, VALUBusy 1.4% -> pure load-latency bound). v8 reverts to
// the 64m x 128n block (8 MFMA : 6 loads per wave k-step) and adds explicit
// 4-deep register batching (24 loads in flight before 32 MFMAs consume them),
// __launch_bounds__(256,2) to allow ~150 VGPRs. Everything else = v7.
//
// ws map (float offsets), total ~62.4 MB:
//   Xbf  @0         [8192][2048] bf16 (8388608 fl) — dead after k2_mfma,
//                   ALIASED by OP @0 [16][4096][128] fp32 (exactly 8388608 fl)
//   HP   @8388608   [2][8192][256] fp32 partials (k2->k3, dead after)
//   Wbf  @12582912  [512][2048] bf16 (W1q rows 0..255, W1r 256..511)
//   Z    @13107200  [8192][128] fp32
//   Zbf  @14155776  [8192][128] bf16
//   ZbfT @14680064  [128][4096] bf16 (Z_r transposed)
//   RB   @14942208  [4096][128]
//   COS  @15466496  [4096]
//   ILW  @15470592  [4096][2]
//   LW   @15478784  [16][4096][2]
// d_out: fp32, [0..4095]=raw_logit, [4096..8191]=delta_theta.

#define HD   2048
#define D2   256
#define DD   128
#define NQ   4096
#define NT   8192

typedef __attribute__((ext_vector_type(8))) short s16x8;
typedef __attribute__((ext_vector_type(4))) float f32x4;

static __device__ __forceinline__ float gelu_exact(float x){
    return 0.5f * x * (1.0f + erff(x * 0.7071067811865475f));
}
static __device__ __forceinline__ unsigned short f2bf(float f){
    unsigned int u = __float_as_uint(f);
    return (unsigned short)((u + 0x7FFFu + ((u >> 16) & 1u)) >> 16);
}
static __device__ __forceinline__ unsigned int pack2bf(float a, float b){
    return (unsigned int)f2bf(a) | ((unsigned int)f2bf(b) << 16);
}

// ---------------- KLN: LN(x) -> bf16 Xbf (blocks 0..8191); W1 -> bf16 Wbf (8192..8703)
__global__ __launch_bounds__(256)
void kLN_cast(const float* __restrict__ q, const float* __restrict__ R,
              const float* __restrict__ gq, const float* __restrict__ bq,
              const float* __restrict__ gr, const float* __restrict__ br,
              const float* __restrict__ W1q, const float* __restrict__ W1r,
              unsigned short* __restrict__ Xbf, unsigned short* __restrict__ Wbf){
    const int r = blockIdx.x;
    const int tid = threadIdx.x;
    if (r >= NT){
        const int rw = r - NT;
        const float* src = (rw >= 256) ? (W1r + (size_t)(rw - 256) * HD)
                                       : (W1q + (size_t)rw * HD);
        float4 a = *(const float4*)&src[tid * 8];
        float4 c = *(const float4*)&src[tid * 8 + 4];
        uint4 p = {pack2bf(a.x, a.y), pack2bf(a.z, a.w),
                   pack2bf(c.x, c.y), pack2bf(c.z, c.w)};
        *(uint4*)&Wbf[(size_t)rw * HD + tid * 8] = p;
        return;
    }
    const float* src = (r < NQ) ? (q + (size_t)r * HD) : (R + (size_t)(r - NQ) * HD);
    const float* g  = (r < NQ) ? gq : gr;
    const float* bb = (r < NQ) ? bq : br;
    float4 x0 = *(const float4*)&src[tid * 8];
    float4 x1 = *(const float4*)&src[tid * 8 + 4];
    float v[8] = {x0.x, x0.y, x0.z, x0.w, x1.x, x1.y, x1.z, x1.w};
    float s = 0.f, sq = 0.f;
#pragma unroll
    for (int i = 0; i < 8; ++i){ s += v[i]; sq += v[i] * v[i]; }
    __shared__ float red[256];
    __shared__ float mS, rS;
    red[tid] = s; __syncthreads();
    for (int off = 128; off > 0; off >>= 1){
        if (tid < off) red[tid] += red[tid + off];
        __syncthreads();
    }
    float sum = red[0]; __syncthreads();
    red[tid] = sq; __syncthreads();
    for (int off = 128; off > 0; off >>= 1){
        if (tid < off) red[tid] += red[tid + off];
        __syncthreads();
    }
    if (tid == 0){
        float mean = sum * (1.0f / HD);
        float var  = red[0] * (1.0f / HD) - mean * mean;
        mS = mean;
        rS = rsqrtf(fmaxf(var, 0.0f) + 1e-5f);
    }
    __syncthreads();
    float mean = mS, rstd = rS;
    float4 g0 = *(const float4*)&g[tid * 8];
    float4 g1 = *(const float4*)&g[tid * 8 + 4];
    float4 b0 = *(const float4*)&bb[tid * 8];
    float4 b1 = *(const float4*)&bb[tid * 8 + 4];
    float gg[8] = {g0.x, g0.y, g0.z, g0.w, g1.x, g1.y, g1.z, g1.w};
    float bv[8] = {b0.x, b0.y, b0.z, b0.w, b1.x, b1.y, b1.z, b1.w};
    float h[8];
#pragma unroll
    for (int i = 0; i < 8; ++i) h[i] = (v[i] - mean) * rstd * gg[i] + bv[i];
    uint4 p = {pack2bf(h[0], h[1]), pack2bf(h[2], h[3]),
               pack2bf(h[4], h[5]), pack2bf(h[6], h[7])};
    *(uint4*)&Xbf[(size_t)r * HD + tid * 8] = p;
}

// ---------------- K2: HP[ks] = Xbf @ Wbf^T (K-half ks), bf16 MFMA.
// grid (128 m-blocks of 64, 2 n-blocks of 128, 2 K-splits), 256 thr = 4 waves.
// Wave: 32m x 64n = 2x4 tiles. 4-deep k-step batching: 24 loads in flight.
__global__ __launch_bounds__(256, 2)
void k2_mfma(const unsigned short* __restrict__ Xbf,
             const unsigned short* __restrict__ Wbf,
             float* __restrict__ HP){
    const int tid  = threadIdx.x;
    const int wave = tid >> 6, lane = tid & 63;
    const int quad = lane >> 4, col = lane & 15;
    const int mblk = blockIdx.x;           // 0..127
    const int nblk = blockIdx.y;           // 0..1
    const int ks   = blockIdx.z;           // 0..1
    const int inp  = mblk >> 6;
    const int mbase = mblk * 64 + (wave & 1) * 32;
    const int nbase = nblk * 128 + (wave >> 1) * 64;

    const unsigned short* A0 = Xbf + (size_t)(mbase + col) * HD + ks * 1024 + quad * 8;
    const unsigned short* A1 = A0 + (size_t)16 * HD;
    const unsigned short* B0 = Wbf + (size_t)(inp * 256 + nbase + col) * HD + ks * 1024 + quad * 8;
    const unsigned short* B1 = B0 + (size_t)16 * HD;
    const unsigned short* B2 = B0 + (size_t)32 * HD;
    const unsigned short* B3 = B0 + (size_t)48 * HD;

    f32x4 acc[2][4];
#pragma unroll
    for (int mi = 0; mi < 2; ++mi)
#pragma unroll
        for (int ni = 0; ni < 4; ++ni) acc[mi][ni] = (f32x4){0.f, 0.f, 0.f, 0.f};

    for (int s = 0; s < 32; s += 4){
        s16x8 av[4][2], bv[4][4];
#pragma unroll
        for (int u = 0; u < 4; ++u){
            const int ko = (s + u) * 32;
            av[u][0] = *(const s16x8*)(A0 + ko);
            av[u][1] = *(const s16x8*)(A1 + ko);
            bv[u][0] = *(const s16x8*)(B0 + ko);
            bv[u][1] = *(const s16x8*)(B1 + ko);
            bv[u][2] = *(const s16x8*)(B2 + ko);
            bv[u][3] = *(const s16x8*)(B3 + ko);
        }
#pragma unroll
        for (int u = 0; u < 4; ++u){
#pragma unroll
            for (int ni = 0; ni < 4; ++ni){
                acc[0][ni] = __builtin_amdgcn_mfma_f32_16x16x32_bf16(av[u][0], bv[u][ni], acc[0][ni], 0, 0, 0);
                acc[1][ni] = __builtin_amdgcn_mfma_f32_16x16x32_bf16(av[u][1], bv[u][ni], acc[1][ni], 0, 0, 0);
            }
        }
    }
    float* dst = HP + (size_t)ks * NT * D2;
#pragma unroll
    for (int mi = 0; mi < 2; ++mi){
#pragma unroll
        for (int ni = 0; ni < 4; ++ni){
#pragma unroll
            for (int reg = 0; reg < 4; ++reg){
                int m = mbase + mi * 16 + quad * 4 + reg;
                int n = nbase + ni * 16 + col;
                dst[(size_t)m * D2 + n] = acc[mi][ni][reg];
            }
        }
    }
}

// ---------------- K3: combine HP + bias + GELU, GEMM2, l2norm -> Z (fp32), Zbf (bf16)
__global__ __launch_bounds__(256)
void k3_gemm2(const float* __restrict__ HP,
              const float* __restrict__ b1q, const float* __restrict__ b1r,
              const float* __restrict__ W2q, const float* __restrict__ b2q,
              const float* __restrict__ W2r, const float* __restrict__ b2r,
              float* __restrict__ Z, unsigned short* __restrict__ Zbf){
    const int gstart = blockIdx.x * 32;
    const int inp = (gstart >= NQ) ? 1 : 0;
    const float* b1 = inp ? b1r : b1q;
    const float* W2 = inp ? W2r : W2q;
    const float* b2 = inp ? b2r : b2q;

    __shared__ __align__(16) float Hs[32][68];
    __shared__ __align__(16) float Wk[64][132];
    __shared__ float red[32][17];
    __shared__ float normS[32];

    const int tid = threadIdx.x;
    const int ty = tid >> 4;
    const int tx = tid & 15;

    float acc[2][8];
#pragma unroll
    for (int jj = 0; jj < 8; ++jj){ acc[0][jj] = 0.f; acc[1][jj] = 0.f; }

    for (int kc = 0; kc < 4; ++kc){
#pragma unroll
        for (int i = 0; i < 8; ++i){
            int e = tid + i * 256;
            int rr = e >> 6, kk = e & 63;
            size_t idx = (size_t)(gstart + rr) * D2 + kc * 64 + kk;
            float hv = HP[idx] + HP[(size_t)NT * D2 + idx] + b1[kc * 64 + kk];
            Hs[rr][kk] = gelu_exact(hv);
        }
#pragma unroll
        for (int i = 0; i < 32; ++i){
            int e = tid + i * 256;
            int nn = e >> 6, kk = e & 63;
            Wk[kk][nn] = W2[(size_t)nn * D2 + kc * 64 + kk];
        }
        __syncthreads();
#pragma unroll
        for (int k4 = 0; k4 < 16; ++k4){
            float a0[4], a1[4];
            float4 t0 = *(const float4*)&Hs[ty * 2][k4 * 4];
            a0[0] = t0.x; a0[1] = t0.y; a0[2] = t0.z; a0[3] = t0.w;
            float4 t1 = *(const float4*)&Hs[ty * 2 + 1][k4 * 4];
            a1[0] = t1.x; a1[1] = t1.y; a1[2] = t1.z; a1[3] = t1.w;
#pragma unroll
            for (int kq = 0; kq < 4; ++kq){
                float4 w0 = *(const float4*)&Wk[k4 * 4 + kq][tx * 8];
                float4 w1 = *(const float4*)&Wk[k4 * 4 + kq][tx * 8 + 4];
                float wv[8] = {w0.x, w0.y, w0.z, w0.w, w1.x, w1.y, w1.z, w1.w};
#pragma unroll
                for (int jj = 0; jj < 8; ++jj){
                    acc[0][jj] += a0[kq] * wv[jj];
                    acc[1][jj] += a1[kq] * wv[jj];
                }
            }
        }
        __syncthreads();
    }
    float v0[8], v1[8];
    float sq0 = 0.f, sq1 = 0.f;
#pragma unroll
    for (int jj = 0; jj < 8; ++jj){
        int c = tx * 8 + jj;
        v0[jj] = acc[0][jj] + b2[c];
        v1[jj] = acc[1][jj] + b2[c];
        sq0 += v0[jj] * v0[jj];
        sq1 += v1[jj] * v1[jj];
    }
    red[ty * 2][tx]     = sq0;
    red[ty * 2 + 1][tx] = sq1;
    __syncthreads();
    if (tid < 32){
        float s = 0.f;
#pragma unroll
        for (int t = 0; t < 16; ++t) s += red[tid][t];
        normS[tid] = 1.0f / fmaxf(sqrtf(s), 1e-12f);
    }
    __syncthreads();
    float s0 = normS[ty * 2], s1 = normS[ty * 2 + 1];
    int row0 = gstart + ty * 2, row1 = row0 + 1;
    size_t o0 = (size_t)row0 * DD + tx * 8;
    size_t o1 = (size_t)row1 * DD + tx * 8;
    float z0[8], z1[8];
#pragma unroll
    for (int jj = 0; jj < 8; ++jj){ z0[jj] = v0[jj] * s0; z1[jj] = v1[jj] * s1; }
    float4 a = {z0[0], z0[1], z0[2], z0[3]}, b = {z0[4], z0[5], z0[6], z0[7]};
    float4 c = {z1[0], z1[1], z1[2], z1[3]}, d = {z1[4], z1[5], z1[6], z1[7]};
    *(float4*)&Z[o0]     = a;  *(float4*)&Z[o0 + 4] = b;
    *(float4*)&Z[o1]     = c;  *(float4*)&Z[o1 + 4] = d;
    uint4 p0 = {pack2bf(z0[0], z0[1]), pack2bf(z0[2], z0[3]),
                pack2bf(z0[4], z0[5]), pack2bf(z0[6], z0[7])};
    uint4 p1 = {pack2bf(z1[0], z1[1]), pack2bf(z1[2], z1[3]),
                pack2bf(z1[4], z1[5]), pack2bf(z1[6], z1[7])};
    *(uint4*)&Zbf[o0] = p0;
    *(uint4*)&Zbf[o1] = p1;
}

// ---------------- KT: ZbfT[d][r] = Zbf[NQ + r][d]  (r part only), tile 64x128.
__global__ __launch_bounds__(256)
void kT_transpose(const unsigned short* __restrict__ Zbf,
                  unsigned short* __restrict__ ZbfT){
    __shared__ unsigned short Ts[64][129];
    const int r0 = blockIdx.x * 64;
    const int tid = threadIdx.x;
#pragma unroll
    for (int i = 0; i < 32; ++i){
        int e = tid + i * 256;
        int rr = e >> 7, dd = e & 127;
        Ts[rr][dd] = Zbf[(size_t)(NQ + r0 + rr) * DD + dd];
    }
    __syncthreads();
#pragma unroll
    for (int i = 0; i < 32; ++i){
        int e = tid + i * 256;
        int dd = e >> 6, rr = e & 63;
        ZbfT[(size_t)dd * NQ + r0 + rr] = Ts[rr][dd];
    }
}

// ---------------- KA: flash attention pass (bf16 MFMA), 16 r-splits.
// grid (64 m-blocks, 16 r-splits), 256 thr = 4 waves, each wave = 16 q rows.
__global__ __launch_bounds__(256)
void kA_attn(const unsigned short* __restrict__ Zbf,
             const unsigned short* __restrict__ ZbfT,
             float* __restrict__ OP, float* __restrict__ LW){
    const int tid  = threadIdx.x;
    const int wave = tid >> 6, lane = tid & 63;
    const int quad = lane >> 4, col = lane & 15;
    const int m0   = blockIdx.x * 64 + wave * 16;
    const int split = blockIdx.y;          // 0..15
    const float scl = 0.08838834764831845f;   // 1/sqrt(128)

    __shared__ __align__(16) unsigned short Pt[4][16][72];  // per-wave [m][r]

    s16x8 aq[4];
#pragma unroll
    for (int kb = 0; kb < 4; ++kb)
        aq[kb] = *(const s16x8*)&Zbf[(size_t)(m0 + col) * DD + kb * 32 + quad * 8];

    f32x4 o[8];
#pragma unroll
    for (int dt = 0; dt < 8; ++dt) o[dt] = (f32x4){0.f, 0.f, 0.f, 0.f};
    float lp[4] = {0.f, 0.f, 0.f, 0.f}, wp[4] = {0.f, 0.f, 0.f, 0.f};

    for (int it = 0; it < 4; ++it){
        const int r0 = split * 256 + it * 64;
#pragma unroll
        for (int nt = 0; nt < 4; ++nt){
            f32x4 s = (f32x4){0.f, 0.f, 0.f, 0.f};
#pragma unroll
            for (int kb = 0; kb < 4; ++kb){
                s16x8 b = *(const s16x8*)&Zbf[(size_t)(NQ + r0 + nt * 16 + col) * DD + kb * 32 + quad * 8];
                s = __builtin_amdgcn_mfma_f32_16x16x32_bf16(aq[kb], b, s, 0, 0, 0);
            }
#pragma unroll
            for (int reg = 0; reg < 4; ++reg){
                float sv = s[reg] * scl;
                float e  = __expf(sv);
                lp[reg] += e;
                wp[reg] += e * sv;
                Pt[wave][quad * 4 + reg][nt * 16 + col] = f2bf(e);
            }
        }
        s16x8 ap[2];
#pragma unroll
        for (int kb2 = 0; kb2 < 2; ++kb2)
            ap[kb2] = *(const s16x8*)&Pt[wave][col][kb2 * 32 + quad * 8];
#pragma unroll
        for (int dt = 0; dt < 8; ++dt){
#pragma unroll
            for (int kb2 = 0; kb2 < 2; ++kb2){
                s16x8 b = *(const s16x8*)&ZbfT[(size_t)(dt * 16 + col) * NQ + r0 + kb2 * 32 + quad * 8];
                o[dt] = __builtin_amdgcn_mfma_f32_16x16x32_bf16(ap[kb2], b, o[dt], 0, 0, 0);
            }
        }
    }
#pragma unroll
    for (int reg = 0; reg < 4; ++reg){
        float l = lp[reg], w = wp[reg];
        l += __shfl_xor(l, 8);  w += __shfl_xor(w, 8);
        l += __shfl_xor(l, 4);  w += __shfl_xor(w, 4);
        l += __shfl_xor(l, 2);  w += __shfl_xor(w, 2);
        l += __shfl_xor(l, 1);  w += __shfl_xor(w, 1);
        if (col == 0){
            int row = m0 + quad * 4 + reg;
            LW[((size_t)split * NQ + row) * 2]     = l;
            LW[((size_t)split * NQ + row) * 2 + 1] = w;
        }
    }
#pragma unroll
    for (int dt = 0; dt < 8; ++dt){
#pragma unroll
        for (int reg = 0; reg < 4; ++reg){
            int row = m0 + quad * 4 + reg;
            OP[((size_t)split * NQ + row) * DD + dt * 16 + col] = o[dt][reg];
        }
    }
}

// ---------------- KC: combine 16 splits -> r_bar, cos, u_n.
__global__ __launch_bounds__(128)
void kC_combine(const float* __restrict__ OP, const float* __restrict__ LW,
                const float* __restrict__ Z,
                float* __restrict__ RB, float* __restrict__ COS,
                float* __restrict__ ILW){
    const int r = blockIdx.x;
    const int c = threadIdx.x;
    float v = 0.f;
#pragma unroll
    for (int s = 0; s < 16; ++s) v += OP[((size_t)s * NQ + r) * DD + c];
    __shared__ float red[128];
    red[c] = v * v; __syncthreads();
    for (int off = 64; off > 0; off >>= 1){
        if (c < off) red[c] += red[c + off];
        __syncthreads();
    }
    float scale = 1.0f / fmaxf(sqrtf(red[0]), 1e-12f);
    __syncthreads();
    float rb = v * scale;
    RB[(size_t)r * DD + c] = rb;
    float zq = Z[(size_t)r * DD + c];
    red[c] = zq * rb; __syncthreads();
    for (int off = 64; off > 0; off >>= 1){
        if (c < off) red[c] += red[c + off];
        __syncthreads();
    }
    if (c == 0){
        COS[r] = red[0];
        float l = 0.f, w = 0.f;
#pragma unroll
        for (int s = 0; s < 16; ++s){
            l += LW[((size_t)s * NQ + r) * 2];
            w += LW[((size_t)s * NQ + r) * 2 + 1];
        }
        float ent = logf(l) - w / l;
        ILW[2 * r]     = 1.0f / l;
        ILW[2 * r + 1] = ent * (1.0f / 8.317766166719343f);  // / ln(4096)
    }
}

// ---------------- K8: decoder MLP (LN -> 256->128 GELU -> 128->1) + scalar heads
__global__ __launch_bounds__(256)
void k8_decoder(const float* __restrict__ Z, const float* __restrict__ RB,
                const float* __restrict__ ILW, const float* __restrict__ COS,
                const float* __restrict__ gd, const float* __restrict__ bd,
                const float* __restrict__ W1d, const float* __restrict__ b1d,
                const float* __restrict__ W2d, const float* __restrict__ b2d,
                const float* __restrict__ beta, const float* __restrict__ W_len,
                const float* __restrict__ b_len,
                float* __restrict__ out){
    const int r0 = blockIdx.x * 16;
    const int tid = threadIdx.x;

    __shared__ __align__(16) float Xk[256][20];
    __shared__ __align__(16) float Wd[32][132];
    __shared__ float Hd[16][132];
    __shared__ float red1[16][17], red2[16][17];
    __shared__ float mS[16], rS[16];

#pragma unroll
    for (int i = 0; i < 16; ++i){
        int e = tid + i * 256;
        int rr = e >> 8, cc = e & 255;
        float v = (cc < DD) ? Z[(size_t)(r0 + rr) * DD + cc]
                            : RB[(size_t)(r0 + rr) * DD + (cc - DD)];
        Xk[cc][rr] = v;
    }
    __syncthreads();
    {
        const int row = tid >> 4, sub = tid & 15;
        float s = 0.f, sq = 0.f;
#pragma unroll
        for (int i = 0; i < 16; ++i){
            float v = Xk[sub + 16 * i][row];
            s += v; sq += v * v;
        }
        red1[row][sub] = s; red2[row][sub] = sq;
        __syncthreads();
        if (sub == 0){
            float ts = 0.f, tq = 0.f;
#pragma unroll
            for (int t = 0; t < 16; ++t){ ts += red1[row][t]; tq += red2[row][t]; }
            float mean = ts * (1.0f / D2);
            float var  = tq * (1.0f / D2) - mean * mean;
            var = fmaxf(var, 0.f);
            mS[row] = mean; rS[row] = rsqrtf(var + 1e-5f);
        }
        __syncthreads();
    }
#pragma unroll
    for (int i = 0; i < 16; ++i){
        int e = tid + i * 256;
        int rr = e >> 8, cc = e & 255;
        float v = Xk[cc][rr];
        Xk[cc][rr] = (v - mS[rr]) * rS[rr] * gd[cc] + bd[cc];
    }
    __syncthreads();

    const int j  = tid & 127;
    const int rh = tid >> 7;
    float hacc[8];
    {
        float bj = b1d[j];
#pragma unroll
        for (int i = 0; i < 8; ++i) hacc[i] = bj;
    }
    for (int kc = 0; kc < 8; ++kc){
#pragma unroll
        for (int i = 0; i < 16; ++i){
            int e = tid + i * 256;
            int nn = e >> 5, kk = e & 31;
            Wd[kk][nn] = W1d[(size_t)nn * D2 + kc * 32 + kk];
        }
        __syncthreads();
#pragma unroll
        for (int k = 0; k < 32; ++k){
            float w = Wd[k][j];
            int kk = kc * 32 + k;
            float4 x0 = *(const float4*)&Xk[kk][rh * 8];
            float4 x1 = *(const float4*)&Xk[kk][rh * 8 + 4];
            hacc[0] += x0.x * w; hacc[1] += x0.y * w;
            hacc[2] += x0.z * w; hacc[3] += x0.w * w;
            hacc[4] += x1.x * w; hacc[5] += x1.y * w;
            hacc[6] += x1.z * w; hacc[7] += x1.w * w;
        }
        __syncthreads();
    }
#pragma unroll
    for (int i = 0; i < 8; ++i) Hd[rh * 8 + i][j] = gelu_exact(hacc[i]);
    __syncthreads();
    {
        const int row = tid >> 4, sub = tid & 15;
        float part = 0.f;
#pragma unroll
        for (int i = 0; i < 8; ++i){
            int jj = sub + 16 * i;
            part += Hd[row][jj] * W2d[jj];
        }
        red1[row][sub] = part;
        __syncthreads();
        if (sub == 0){
            float lg = b2d[0];
#pragma unroll
            for (int t = 0; t < 16; ++t) lg += red1[row][t];
            int gr = r0 + row;
            float u  = ILW[2 * gr + 1];
            float cv = COS[gr];
            float dln = cv * W_len[0] + u * W_len[1] + b_len[0];
            float dt = beta[0] * u + beta[1] * tanhf(dln);
            dt = fminf(0.5f, fmaxf(-0.5f, dt));
            out[gr]      = lg;
            out[NQ + gr] = dt;
        }
    }
}

extern "C" void kernel_launch(void* const* d_in, const int* in_sizes, int n_in,
                              void* d_out, int out_size, void* d_ws, size_t ws_size,
                              hipStream_t stream){
    const float* q      = (const float*)d_in[0];
    const float* R      = (const float*)d_in[1];
    const float* ln_q_g = (const float*)d_in[2];
    const float* ln_q_b = (const float*)d_in[3];
    const float* W1q    = (const float*)d_in[4];
    const float* b1q    = (const float*)d_in[5];
    const float* W2q    = (const float*)d_in[6];
    const float* b2q    = (const float*)d_in[7];
    const float* ln_r_g = (const float*)d_in[8];
    const float* ln_r_b = (const float*)d_in[9];
    const float* W1r    = (const float*)d_in[10];
    const float* b1r    = (const float*)d_in[11];
    const float* W2r    = (const float*)d_in[12];
    const float* b2r    = (const float*)d_in[13];
    const float* ln_d_g = (const float*)d_in[14];
    const float* ln_d_b = (const float*)d_in[15];
    const float* W1d    = (const float*)d_in[16];
    const float* b1d    = (const float*)d_in[17];
    const float* W2d    = (const float*)d_in[18];
    const float* b2d    = (const float*)d_in[19];
    const float* beta   = (const float*)d_in[20];
    const float* W_len  = (const float*)d_in[21];
    const float* b_len  = (const float*)d_in[22];

    float* WS = (float*)d_ws;
    unsigned short* Xbf  = (unsigned short*)(WS);             // 8192*2048 bf16 = 8388608 fl
    float* OP    = WS;                                        // [16][4096][128] aliases dead Xbf
    float* HP    = WS + 8388608;                              // 2*8192*256
    unsigned short* Wbf  = (unsigned short*)(WS + 12582912);  // 512*2048 bf16
    float* Z     = WS + 13107200;                             // 8192*128
    unsigned short* Zbf  = (unsigned short*)(WS + 14155776);  // 8192*128 bf16
    unsigned short* ZbfT = (unsigned short*)(WS + 14680064);  // 128*4096 bf16
    float* RB    = WS + 14942208;                             // 4096*128
    float* COSV  = WS + 15466496;                             // 4096
    float* ILW   = WS + 15470592;                             // 4096*2
    float* LW    = WS + 15478784;                             // 16*4096*2
    float* out   = (float*)d_out;

    hipLaunchKernelGGL(kLN_cast, dim3(NT + 512), dim3(256), 0, stream,
                       q, R, ln_q_g, ln_q_b, ln_r_g, ln_r_b, W1q, W1r, Xbf, Wbf);
    hipLaunchKernelGGL(k2_mfma, dim3(128, 2, 2), dim3(256), 0, stream, Xbf, Wbf, HP);
    hipLaunchKernelGGL(k3_gemm2, dim3(256), dim3(256), 0, stream,
                       HP, b1q, b1r, W2q, b2q, W2r, b2r, Z, Zbf);
    hipLaunchKernelGGL(kT_transpose, dim3(64), dim3(256), 0, stream, Zbf, ZbfT);
    hipLaunchKernelGGL(kA_attn, dim3(64, 16), dim3(256), 0, stream, Zbf, ZbfT, OP, LW);
    hipLaunchKernelGGL(kC_combine, dim3(NQ), dim3(128), 0, stream, OP, LW, Z, RB, COSV, ILW);
    hipLaunchKernelGGL(k8_decoder, dim3(256), dim3(256), 0, stream,
                       Z, RB, ILW, COSV, ln_d_g, ln_d_b, W1d, b1d, W2d, b2d,
                       beta, W_len, b_len, out);
}